// Round 9
// baseline (389.237 us; speedup 1.0000x reference)
//
#include <hip/hip_runtime.h>
#include <hip/hip_bf16.h>
#include <cstdint>

#define QLEN   1024
#define KLEN   2048
#define DMODEL 2048
#define BATCH  4
#define FLEN   (KLEN - QLEN + 1)   // 1025

typedef __bf16 bf16x8 __attribute__((ext_vector_type(8)));
typedef float  f32x4  __attribute__((ext_vector_type(4)));

// Static fallbacks (ws placement is the measured-faster primary, round 3).
__device__ __align__(16) __bf16 g_ft[(size_t)QLEN * KLEN];           // 4 MiB
__device__ __align__(16) __bf16 g_yt[(size_t)BATCH * DMODEL * KLEN]; // 32 MiB
__device__ int g_flags[8];

typedef __attribute__((address_space(1))) void gvoid;
typedef __attribute__((address_space(3))) void svoid;

__device__ __forceinline__ void async_load16(const void* g, void* lds) {
  gvoid* gp = (gvoid*)(uintptr_t)g;
  svoid* sp = (svoid*)(uint32_t)(uintptr_t)lds;   // flat LDS addr low 32 bits == LDS offset
  __builtin_amdgcn_global_load_lds(gp, sp, 16, 0, 0);
}

// ---------------- fused pipeline (round-9: hardened round-8) ----------------
// R8 hang diagnosis: __launch_bounds__(256) does NOT cap VGPR; if allocator
// exceeded ~170 VGPR -> 2 blocks/CU = 512 slots = #spinners -> adversarial
// dispatch order can fill all slots with spinners -> deadlock -> watchdog.
// Fix: __launch_bounds__(256,4) caps VGPR at 128 -> >=4 blocks/CU -> >=1024
// slots; spinners <=512 -> >=512 slots always hold runnable producers ->
// forward progress under ANY dispatch order. Grid reordered so all producers
// dispatch before any spinner (helps speed; correctness order-independent).
//   grid = [ft 256 | yt 1024 (b major) | gemm 512 (b major)]
// Bodies = proven R3 prep / R6 gemm, bit-identical math.
#define BM 128
#define BN 128
#define BK 64

#define FT_BLOCKS  256
#define YT_BLOCKS  (BATCH * 256)     // 1024
#define GEMM_PER_B 128               // 8 bm x 16 bn
#define GRID_TOTAL (FT_BLOCKS + YT_BLOCKS + BATCH * GEMM_PER_B)   // 1792

__global__ void init_flags_kernel(int* flagsp) {
  int* flags = flagsp ? flagsp : g_flags;
  if (threadIdx.x < 8) flags[threadIdx.x] = 0;
}

__global__ __launch_bounds__(256, 4) void fused_kernel(const float* __restrict__ x,
                                                       const float* __restrict__ p,
                                                       const int* __restrict__ addp,
                                                       __bf16* __restrict__ ftp,
                                                       __bf16* __restrict__ ytp,
                                                       int* __restrict__ flagsp,
                                                       float* __restrict__ out) {
  __shared__ __align__(16) __bf16 As[BM * BK];   // gemm role only, 16 KB
  __shared__ __align__(16) __bf16 Bs[BN * BK];   // gemm role only, 16 KB
  __bf16* ft = ftp ? ftp : g_ft;
  __bf16* yt = ytp ? ytp : g_yt;
  int* flags = flagsp ? flagsp : g_flags;
  const int tid  = threadIdx.x;
  const int lane = tid & 63;
  const int wave = tid >> 6;
  const int bid  = blockIdx.x;

  if (bid < FT_BLOCKS) {
    // ---- FT role: 4 sweeps x 256 chunks. FT[l,m] =
    // cos(2*pi*((l*(m-l))%1025)/1025)/sqrt(1025*2048) inside band.
    const float w     = 6.283185307179586f / (float)FLEN;
    const float scale = 1.0f / sqrtf((float)FLEN * (float)KLEN);
#pragma unroll
    for (int s = 0; s < 4; ++s) {
      const int uu = bid * 1024 + s * 256 + tid;   // [0, QLEN*KLEN/8)
      const int l  = uu >> 8;
      const int m0 = (uu & 255) * 8;
      const int j0 = m0 - l;
      bf16x8 o = {};
      if (j0 + 7 >= 0 && j0 < FLEN) {
#pragma unroll
        for (int i = 0; i < 8; ++i) {
          const int j = j0 + i;
          float vv = 0.0f;
          if (j >= 0 && j < FLEN) {
            const int rr = (l * j) % FLEN;         // exact: l*j < 2^20
            vv = cosf((float)rr * w) * scale;
          }
          o[i] = (__bf16)vv;
        }
      }
      *(bf16x8*)(ft + (size_t)uu * 8) = o;
    }
    __syncthreads();                               // per-wave vmcnt drained
    if (tid == 0) {
      __threadfence();                             // device-scope release (L2 writeback)
      __hip_atomic_fetch_add(&flags[4], 1, __ATOMIC_RELEASE, __HIP_MEMORY_SCOPE_AGENT);
    }
    return;
  }

  if (bid < FT_BLOCKS + YT_BLOCKS) {
    // ---- y^T role (R3 body): block = (b, mt); 32 d-units, 8 per wave.
    const int idx = bid - FT_BLOCKS;
    const int b = idx >> 8, mt = idx & 255;
    const int doadd = *addp;
    __bf16* outp = yt + ((size_t)b * 256 + mt) * (size_t)(DMODEL * 8);
#pragma unroll
    for (int q = 0; q < 8; ++q) {
      const int d = (wave * 8 + q) * 64 + lane;
      const float* xp = x + ((size_t)b * KLEN + mt * 8) * DMODEL + d;
      float v[8];
#pragma unroll
      for (int i = 0; i < 8; ++i) v[i] = xp[(size_t)i * DMODEL];  // 256 B/instr coalesced
      if (doadd) {
        const float* pp = p + ((size_t)b * KLEN + mt * 8) * DMODEL + d;
#pragma unroll
        for (int i = 0; i < 8; ++i) v[i] += pp[(size_t)i * DMODEL];
      }
      bf16x8 o;
#pragma unroll
      for (int i = 0; i < 8; ++i) o[i] = (__bf16)v[i];
      *(bf16x8*)(outp + (size_t)d * 8) = o;        // wave: contiguous 1 KB
    }
    __syncthreads();
    if (tid == 0) {
      __threadfence();
      __hip_atomic_fetch_add(&flags[b], 1, __ATOMIC_RELEASE, __HIP_MEMORY_SCOPE_AGENT);
    }
    return;
  }

  // ---- GEMM role: out[b][l][d] = sum_m FT[l][m] * yt[m][d]
  const int gidx = bid - FT_BLOCKS - YT_BLOCKS;    // 0..511
  const int b = gidx >> 7;
  const int inner = gidx & 127;
  const int bm = inner >> 4, bn = inner & 15;
  // Wait for ft + this batch's yt (agent-scope acquire; s_sleep while spinning).
  if (tid == 0) {
    while (__hip_atomic_load(&flags[4], __ATOMIC_ACQUIRE, __HIP_MEMORY_SCOPE_AGENT) < FT_BLOCKS)
      __builtin_amdgcn_s_sleep(8);
    while (__hip_atomic_load(&flags[b], __ATOMIC_ACQUIRE, __HIP_MEMORY_SCOPE_AGENT) < 256)
      __builtin_amdgcn_s_sleep(8);
  }
  __syncthreads();
  __threadfence();   // acquire: invalidate caches before reading ft/yt

  const int l0 = bm * BM, d0 = bn * BN;
  const int wr = wave >> 1, wc = wave & 1;
  const int col = lane & 15, quad = lane >> 4;
  f32x4 acc[4][4] = {};

  // band: FT[l,m] nonzero only for l <= m <= l+1024 -> 18 K-tiles
  const int t0 = l0 >> 6;
  const int t1 = (l0 + BM - 1 + FLEN - 1) >> 6;    // inclusive
  const __bf16* ftb = ft;
  const __bf16* ytb = yt + (size_t)b * DMODEL * KLEN;  // blocked [mt][d][8]

  for (int t = t0; t <= t1; ++t) {
    const int k0 = t * BK;
    // Stage A (FT): row-major, XOR swizzle on the GLOBAL side (LDS linear).
#pragma unroll
    for (int s = 0; s < 4; ++s) {
      const int cb  = wave * 256 + s * 64;
      const int lc  = cb + lane;
      const int row = lc >> 3;
      const int gc8 = (lc & 7) ^ (row & 7);
      async_load16(ftb + (size_t)(l0 + row) * KLEN + k0 + gc8 * 8, As + cb * 8);
    }
    // Stage B (blocked y^T): chunk-major LDS; contiguous 1 KB source reads.
#pragma unroll
    for (int s = 0; s < 4; ++s) {
      const int idx = wave * 256 + s * 64 + lane;  // 0..1023
      const int c   = idx >> 7;
      const int dd  = idx & 127;
      async_load16(ytb + ((size_t)(t * 8 + c) * DMODEL + (d0 + dd)) * 8, Bs + (size_t)idx * 8);
    }
    __syncthreads();

#pragma unroll
    for (int kk = 0; kk < 2; ++kk) {
      bf16x8 af[4], bq[4];
      const int c8 = kk * 4 + quad;
#pragma unroll
      for (int ti = 0; ti < 4; ++ti) {
        const int r = wr * 64 + ti * 16 + col;
        af[ti] = *(const bf16x8*)(As + (size_t)((r << 3) + (c8 ^ (r & 7))) * 8);
      }
#pragma unroll
      for (int tj = 0; tj < 4; ++tj) {
        const int r = wc * 64 + tj * 16 + col;
        bq[tj] = *(const bf16x8*)(Bs + (size_t)((c8 << 7) + r) * 8);
      }
#pragma unroll
      for (int ti = 0; ti < 4; ++ti)
#pragma unroll
        for (int tj = 0; tj < 4; ++tj)
          acc[ti][tj] = __builtin_amdgcn_mfma_f32_16x16x32_bf16(af[ti], bq[tj], acc[ti][tj], 0, 0, 0);
    }
    __syncthreads();
  }

  // Epilogue: C/D layout col = lane&15, row = quad*4 + reg  [m89/m91 verified]
#pragma unroll
  for (int ti = 0; ti < 4; ++ti) {
    const int l = l0 + wr * 64 + ti * 16 + quad * 4;
#pragma unroll
    for (int tj = 0; tj < 4; ++tj) {
      const int d = d0 + wc * 64 + tj * 16 + col;
      float* op = out + (size_t)b * QLEN * DMODEL + (size_t)l * DMODEL + d;
#pragma unroll
      for (int r2 = 0; r2 < 4; ++r2) op[(size_t)r2 * DMODEL] = acc[ti][tj][r2];
    }
  }
}

extern "C" void kernel_launch(void* const* d_in, const int* in_sizes, int n_in,
                              void* d_out, int out_size, void* d_ws, size_t ws_size,
                              hipStream_t stream) {
  const float* x   = (const float*)d_in[0];
  const float* p   = (const float*)d_in[1];
  const int* addp  = (const int*)d_in[3];   // add_position (qlen fixed at 1024 by shapes)
  float* out = (float*)d_out;

  // ws placement (round-3 measured win). Everything in ws is fully rewritten
  // (ft/yt) or zero-init'd (flags) each launch before any read -> poison-safe.
  const size_t FT_BYTES = (size_t)QLEN * KLEN * sizeof(__bf16);            // 4 MiB
  const size_t YT_BYTES = (size_t)BATCH * DMODEL * KLEN * sizeof(__bf16);  // 32 MiB
  __bf16* ft = nullptr;
  __bf16* yt = nullptr;
  int* flags = nullptr;   // nullptr -> device falls back to BSS g_flags
  char* ws = (char*)d_ws;
  if (ws && ws_size >= FT_BYTES + YT_BYTES + 256) {
    ft = (__bf16*)ws;
    yt = (__bf16*)(ws + FT_BYTES);
    flags = (int*)(ws + FT_BYTES + YT_BYTES);
  } else if (ws && ws_size >= FT_BYTES + YT_BYTES) {
    ft = (__bf16*)ws;
    yt = (__bf16*)(ws + FT_BYTES);
  } else if (ws && ws_size >= YT_BYTES) {
    yt = (__bf16*)ws;
  }

  init_flags_kernel<<<dim3(1), dim3(64), 0, stream>>>(flags);
  fused_kernel<<<dim3(GRID_TOTAL), dim3(256), 0, stream>>>(x, p, addp, ft, yt, flags, out);
}